// Round 2
// baseline (42.671 us; speedup 1.0000x reference)
//
#include <hip/hip_runtime.h>

#define F_IN 64
#define KHEADS 4

// Kernel 1: p[node][0:4] = x[node] . att[k][0:64]   (src proj, k=0..3)
//           p[node][4:8] = x[node] . att[k][64:128] (tgt proj, k=0..3)
// One wave (64 lanes) per node; lane l owns feature l.
__global__ void proj_kernel(const float* __restrict__ x,
                            const float* __restrict__ att,
                            float* __restrict__ p,
                            int n_nodes) {
    const int lane  = threadIdx.x & 63;
    const int wid   = (int)(blockIdx.x * (blockDim.x >> 6)) + (threadIdx.x >> 6);
    const int nwav  = (int)(gridDim.x * (blockDim.x >> 6));

    // Hoisted per-lane attention weights (att is 4 x 128, row-major)
    const float a0 = att[0 * 128 + lane];
    const float a1 = att[1 * 128 + lane];
    const float a2 = att[2 * 128 + lane];
    const float a3 = att[3 * 128 + lane];
    const float b0 = att[0 * 128 + 64 + lane];
    const float b1 = att[1 * 128 + 64 + lane];
    const float b2 = att[2 * 128 + 64 + lane];
    const float b3 = att[3 * 128 + 64 + lane];

    for (int node = wid; node < n_nodes; node += nwav) {
        const float v = x[(size_t)node * F_IN + lane];
        float r0 = v * a0, r1 = v * a1, r2 = v * a2, r3 = v * a3;
        float r4 = v * b0, r5 = v * b1, r6 = v * b2, r7 = v * b3;
        #pragma unroll
        for (int off = 32; off >= 1; off >>= 1) {
            r0 += __shfl_xor(r0, off, 64);
            r1 += __shfl_xor(r1, off, 64);
            r2 += __shfl_xor(r2, off, 64);
            r3 += __shfl_xor(r3, off, 64);
            r4 += __shfl_xor(r4, off, 64);
            r5 += __shfl_xor(r5, off, 64);
            r6 += __shfl_xor(r6, off, 64);
            r7 += __shfl_xor(r7, off, 64);
        }
        if (lane == 0) {
            float4* pp = (float4*)(p + (size_t)node * 8);
            pp[0] = make_float4(r0, r1, r2, r3);
            pp[1] = make_float4(r4, r5, r6, r7);
        }
    }
}

// Kernel 2: out[e][k] = relu(p[src[e]][k] + p[tgt[e]][4+k])
__global__ void edge_kernel(const int* __restrict__ eidx,
                            const float* __restrict__ p,
                            float* __restrict__ out,
                            int n_edges) {
    const int e = (int)(blockIdx.x * blockDim.x + threadIdx.x);
    if (e >= n_edges) return;
    const int s = eidx[e];
    const int t = eidx[(size_t)n_edges + e];
    const float4 ps = *(const float4*)(p + (size_t)s * 8);
    const float4 pt = *(const float4*)(p + (size_t)t * 8 + 4);
    float4 o;
    o.x = fmaxf(ps.x + pt.x, 0.0f);
    o.y = fmaxf(ps.y + pt.y, 0.0f);
    o.z = fmaxf(ps.z + pt.z, 0.0f);
    o.w = fmaxf(ps.w + pt.w, 0.0f);
    *(float4*)(out + (size_t)e * 4) = o;
}

extern "C" void kernel_launch(void* const* d_in, const int* in_sizes, int n_in,
                              void* d_out, int out_size, void* d_ws, size_t ws_size,
                              hipStream_t stream) {
    const float* x    = (const float*)d_in[0];
    const int*   eidx = (const int*)d_in[1];    // harness delivers integer inputs as int32
    const float* att  = (const float*)d_in[2];
    float*       out  = (float*)d_out;
    float*       p    = (float*)d_ws;           // n_nodes * 8 floats = 1.6 MB

    const int n_nodes = in_sizes[0] / F_IN;     // 50000
    const int n_edges = in_sizes[1] / 2;        // 800000

    // Kernel 1: grid-stride, 4 waves/block
    const int blocks1 = 2048;
    proj_kernel<<<blocks1, 256, 0, stream>>>(x, att, p, n_nodes);

    // Kernel 2: one thread per edge
    const int blocks2 = (n_edges + 255) / 256;
    edge_kernel<<<blocks2, 256, 0, stream>>>(eidx, p, out, n_edges);
}

// Round 4
// 22.601 us; speedup vs baseline: 1.8880x; 1.8880x over previous
//
#include <hip/hip_runtime.h>

#define F_IN 64
#define KHEADS 4

typedef float float4v __attribute__((ext_vector_type(4)));  // native vector: ok for nontemporal builtins

// Kernel 1 (v2): thread-per-node projection.
// p[node][k]   = x[node] . att[k][0:64]    k=0..3
// p[node][4+k] = x[node] . att[k][64:128]
// att (4x128 = 512 floats) staged in LDS, read as same-address broadcasts.
__global__ __launch_bounds__(256) void proj_kernel(const float4v* __restrict__ x4,
                                                   const float4v* __restrict__ att4,
                                                   float4v* __restrict__ p4,
                                                   int n_nodes) {
    __shared__ float4v att_s[128];             // 4 heads x 32 float4
    if (threadIdx.x < 128) att_s[threadIdx.x] = att4[threadIdx.x];
    __syncthreads();

    const int node = (int)(blockIdx.x * blockDim.x + threadIdx.x);
    if (node >= n_nodes) return;

    float acc0 = 0.f, acc1 = 0.f, acc2 = 0.f, acc3 = 0.f;
    float acc4 = 0.f, acc5 = 0.f, acc6 = 0.f, acc7 = 0.f;
    const float4v* row = x4 + (size_t)node * 16;   // 64 floats = 16 float4

    #pragma unroll
    for (int j = 0; j < 16; ++j) {
        const float4v xv = row[j];
        {
            const float4v a = att_s[0*32 + j];      // att[0][4j..]
            acc0 += xv.x*a.x + xv.y*a.y + xv.z*a.z + xv.w*a.w;
            const float4v b = att_s[0*32 + 16 + j]; // att[0][64+4j..]
            acc4 += xv.x*b.x + xv.y*b.y + xv.z*b.z + xv.w*b.w;
        }
        {
            const float4v a = att_s[1*32 + j];
            acc1 += xv.x*a.x + xv.y*a.y + xv.z*a.z + xv.w*a.w;
            const float4v b = att_s[1*32 + 16 + j];
            acc5 += xv.x*b.x + xv.y*b.y + xv.z*b.z + xv.w*b.w;
        }
        {
            const float4v a = att_s[2*32 + j];
            acc2 += xv.x*a.x + xv.y*a.y + xv.z*a.z + xv.w*a.w;
            const float4v b = att_s[2*32 + 16 + j];
            acc6 += xv.x*b.x + xv.y*b.y + xv.z*b.z + xv.w*b.w;
        }
        {
            const float4v a = att_s[3*32 + j];
            acc3 += xv.x*a.x + xv.y*a.y + xv.z*a.z + xv.w*a.w;
            const float4v b = att_s[3*32 + 16 + j];
            acc7 += xv.x*b.x + xv.y*b.y + xv.z*b.z + xv.w*b.w;
        }
    }

    float4v lo = {acc0, acc1, acc2, acc3};
    float4v hi = {acc4, acc5, acc6, acc7};
    p4[(size_t)node * 2]     = lo;
    p4[(size_t)node * 2 + 1] = hi;
}

// Kernel 2: out[e][k] = relu(p[src[e]][k] + p[tgt[e]][4+k])
__global__ __launch_bounds__(256) void edge_kernel(const int* __restrict__ eidx,
                                                   const float* __restrict__ p,
                                                   float* __restrict__ out,
                                                   int n_edges) {
    const int e = (int)(blockIdx.x * blockDim.x + threadIdx.x);
    if (e >= n_edges) return;
    const int s = __builtin_nontemporal_load(eidx + e);
    const int t = __builtin_nontemporal_load(eidx + (size_t)n_edges + e);
    const float4v ps = *(const float4v*)(p + (size_t)s * 8);
    const float4v pt = *(const float4v*)(p + (size_t)t * 8 + 4);
    float4v o;
    o.x = fmaxf(ps.x + pt.x, 0.0f);
    o.y = fmaxf(ps.y + pt.y, 0.0f);
    o.z = fmaxf(ps.z + pt.z, 0.0f);
    o.w = fmaxf(ps.w + pt.w, 0.0f);
    __builtin_nontemporal_store(o, (float4v*)(out + (size_t)e * 4));
}

extern "C" void kernel_launch(void* const* d_in, const int* in_sizes, int n_in,
                              void* d_out, int out_size, void* d_ws, size_t ws_size,
                              hipStream_t stream) {
    const float* x    = (const float*)d_in[0];
    const int*   eidx = (const int*)d_in[1];    // harness delivers integer inputs as int32
    const float* att  = (const float*)d_in[2];
    float*       out  = (float*)d_out;
    float*       p    = (float*)d_ws;           // n_nodes * 8 floats = 1.6 MB

    const int n_nodes = in_sizes[0] / F_IN;     // 50000
    const int n_edges = in_sizes[1] / 2;        // 800000

    // Kernel 1: one thread per node
    const int blocks1 = (n_nodes + 255) / 256;
    proj_kernel<<<blocks1, 256, 0, stream>>>((const float4v*)x, (const float4v*)att,
                                             (float4v*)p, n_nodes);

    // Kernel 2: one thread per edge
    const int blocks2 = (n_edges + 255) / 256;
    edge_kernel<<<blocks2, 256, 0, stream>>>(eidx, p, out, n_edges);
}

// Round 5
// 20.828 us; speedup vs baseline: 2.0487x; 1.0851x over previous
//
#include <hip/hip_runtime.h>

#define F_IN 64
#define KHEADS 4

typedef float float4v __attribute__((ext_vector_type(4)));

// Kernel 1 (v3): 8 lanes per node, fully coalesced x reads.
// Lane sub (0..7) owns features [sub*4, sub*4+4) and [32+sub*4, 32+sub*4+4).
// 3-stage butterfly within each 8-lane group reduces the partial dots.
// p_src[node][k] = x[node].att[k][0:64], p_tgt[node][k] = x[node].att[k][64:128]
__global__ __launch_bounds__(256) void proj_kernel(const float4v* __restrict__ x4,
                                                   const float4v* __restrict__ att4,
                                                   float4v* __restrict__ ps4,
                                                   float4v* __restrict__ pt4,
                                                   int n_nodes) {
    __shared__ float4v att_s[128];             // 4 heads x 128 floats
    if (threadIdx.x < 128) att_s[threadIdx.x] = att4[threadIdx.x];
    __syncthreads();

    const int gid  = (int)(blockIdx.x * blockDim.x + threadIdx.x);
    const int node = gid >> 3;
    const int sub  = gid & 7;
    if (node >= n_nodes) return;

    // Coalesced: at each load, 8 consecutive lanes cover 128 contiguous bytes.
    const float4v xv0 = x4[(size_t)node * 16 + sub];        // elems sub*4 ..
    const float4v xv1 = x4[(size_t)node * 16 + 8 + sub];    // elems 32+sub*4 ..

    float acc[8];
    #pragma unroll
    for (int k = 0; k < KHEADS; ++k) {
        const float4v a0 = att_s[k * 32 + sub];          // att[k][sub*4..]
        const float4v a1 = att_s[k * 32 + 8 + sub];      // att[k][32+sub*4..]
        const float4v b0 = att_s[k * 32 + 16 + sub];     // att[k][64+sub*4..]
        const float4v b1 = att_s[k * 32 + 24 + sub];     // att[k][96+sub*4..]
        acc[k]          = xv0.x*a0.x + xv0.y*a0.y + xv0.z*a0.z + xv0.w*a0.w
                        + xv1.x*a1.x + xv1.y*a1.y + xv1.z*a1.z + xv1.w*a1.w;
        acc[KHEADS + k] = xv0.x*b0.x + xv0.y*b0.y + xv0.z*b0.z + xv0.w*b0.w
                        + xv1.x*b1.x + xv1.y*b1.y + xv1.z*b1.z + xv1.w*b1.w;
    }

    // Butterfly reduce across the 8-lane group (masks 1,2,4 stay in-group).
    #pragma unroll
    for (int m = 1; m < 8; m <<= 1) {
        #pragma unroll
        for (int i = 0; i < 8; ++i) acc[i] += __shfl_xor(acc[i], m, 64);
    }

    if (sub == 0) {
        float4v lo; lo.x = acc[0]; lo.y = acc[1]; lo.z = acc[2]; lo.w = acc[3];
        ps4[node] = lo;
    } else if (sub == 1) {
        float4v hi; hi.x = acc[4]; hi.y = acc[5]; hi.z = acc[6]; hi.w = acc[7];
        pt4[node] = hi;
    }
}

// Kernel 2: out[e][k] = relu(p_src[src[e]][k] + p_tgt[tgt[e]][k])
__global__ __launch_bounds__(256) void edge_kernel(const int* __restrict__ eidx,
                                                   const float4v* __restrict__ ps4,
                                                   const float4v* __restrict__ pt4,
                                                   float* __restrict__ out,
                                                   int n_edges) {
    const int e = (int)(blockIdx.x * blockDim.x + threadIdx.x);
    if (e >= n_edges) return;
    const int s = __builtin_nontemporal_load(eidx + e);
    const int t = __builtin_nontemporal_load(eidx + (size_t)n_edges + e);
    const float4v ps = ps4[s];
    const float4v pt = pt4[t];
    float4v o;
    o.x = fmaxf(ps.x + pt.x, 0.0f);
    o.y = fmaxf(ps.y + pt.y, 0.0f);
    o.z = fmaxf(ps.z + pt.z, 0.0f);
    o.w = fmaxf(ps.w + pt.w, 0.0f);
    __builtin_nontemporal_store(o, (float4v*)(out + (size_t)e * 4));
}

extern "C" void kernel_launch(void* const* d_in, const int* in_sizes, int n_in,
                              void* d_out, int out_size, void* d_ws, size_t ws_size,
                              hipStream_t stream) {
    const float* x    = (const float*)d_in[0];
    const int*   eidx = (const int*)d_in[1];    // harness delivers integer inputs as int32
    const float* att  = (const float*)d_in[2];
    float*       out  = (float*)d_out;

    const int n_nodes = in_sizes[0] / F_IN;     // 50000
    const int n_edges = in_sizes[1] / 2;        // 800000

    // Split projection tables: 800 KB each, 16B-aligned.
    float4v* ps4 = (float4v*)d_ws;
    float4v* pt4 = (float4v*)((char*)d_ws + (size_t)n_nodes * 4 * sizeof(float));

    // Kernel 1: 8 threads per node
    const int threads1 = n_nodes * 8;
    const int blocks1  = (threads1 + 255) / 256;
    proj_kernel<<<blocks1, 256, 0, stream>>>((const float4v*)x, (const float4v*)att,
                                             ps4, pt4, n_nodes);

    // Kernel 2: one thread per edge
    const int blocks2 = (n_edges + 255) / 256;
    edge_kernel<<<blocks2, 256, 0, stream>>>(eidx, ps4, pt4, out, n_edges);
}